// Round 16
// baseline (98.465 us; speedup 1.0000x reference)
//
#include <hip/hip_runtime.h>
#include <hip/hip_fp16.h>

#define HH 128
#define WW 128
#define HW (HH*WW)
#define XT_BYTES ((size_t)8 * HW * 64 * 2)   // x_t f16 NHWC
#define WT_BYTES ((size_t)9 * 2 * 4 * 64 * 8 * 2)

typedef __attribute__((ext_vector_type(8))) short short8;
typedef __attribute__((ext_vector_type(4))) float f32x4;
typedef _Float16 half8 __attribute__((ext_vector_type(8)));

static __device__ __forceinline__ unsigned short f2bf(float f) {
    unsigned int u = __float_as_uint(f);
    u += 0x7fffu + ((u >> 16) & 1u);
    return (unsigned short)(u >> 16);
}
static __device__ __forceinline__ unsigned pkrtz(float lo, float hi) {
    auto r = __builtin_amdgcn_cvt_pkrtz(lo, hi);   // __fp16 ext_vector(2)
    return *(unsigned*)&r;
}

// weight (64,64,3,3) fp32 -> f16 B-fragment layout wt[tap][kf][cot][lane][e]
__global__ void wtrans_kernel(const float* __restrict__ w, unsigned short* __restrict__ wt) {
    int i = blockIdx.x * 256 + threadIdx.x;
    if (i < 9 * 2 * 4 * 64 * 8) {
        int e  = i & 7;
        int l  = (i >> 3) & 63;
        int wv = (i >> 9) & 3;
        int kf = (i >> 11) & 1;
        int k  = i >> 12;
        int co = wv * 16 + (l & 15);
        int c  = kf * 32 + (l >> 4) * 8 + e;
        __half hh = __float2half_rn(w[(co * 64 + c) * 9 + k]);
        wt[i] = __half_as_ushort(hh);
    }
}

// x [8,64,128,128] f32 -> x_t [8,HW,64] f16 (NHWC). Block: 64 hw x 64 ch.
__global__ __launch_bounds__(256) void xtrans_kernel(const float* __restrict__ x,
                                                     unsigned int* __restrict__ xt32) {
    __shared__ float tile[64][65];
    const int bid = blockIdx.x;
    const int b   = bid >> 8;
    const int hw0 = (bid & 255) << 6;
    const int t   = threadIdx.x;
    #pragma unroll
    for (int i = 0; i < 16; ++i) {
        int idx = (i << 8) + t;
        int c = idx >> 6, j = idx & 63;
        tile[c][j] = x[(size_t)(((b << 6) + c) << 14) + hw0 + j];
    }
    __syncthreads();
    #pragma unroll
    for (int i = 0; i < 8; ++i) {
        int idx = (i << 8) + t;
        int cp = idx & 31, hw = idx >> 5;
        xt32[((size_t)((b << 14) + hw0 + hw) << 5) + cp] =
            pkrtz(tile[2 * cp][hw], tile[2 * cp + 1][hw]);
    }
}

// Fast path: block = 64 px, 4 waves; wave wv owns px [16wv,16wv+16) x ALL 64 couts.
// Sampler lane mapping == MFMA A-fragment mapping (px = l&15, ch = (l>>4)*8 [+32]):
// combined bilinear output IS the A-fragment -> NO LDS round-trip, NO barriers in main loop.
__global__ __launch_bounds__(256, 6) void deform_nhwc(
    const unsigned short* __restrict__ xt,  // [8][HW][64] f16
    const float* __restrict__ off,
    const float* __restrict__ msk,
    const unsigned short* __restrict__ wt,  // packed f16 B-fragments
    const float* __restrict__ bias,
    float* __restrict__ out)
{
    // [0,16384): epilogue transpose tile only (unused during main loop)
    // [16384,20992): moSu ushort4 corner hw-indices [9*64]  (byte off = idx<<7)
    // [20992,25600): mwH uint2 packed fp16 weight pairs [9*64]
    __shared__ __align__(16) unsigned char smem[25600];
    ushort4* moSu = (ushort4*)(smem + 16384);
    uint2*   mwH  = (uint2*)(smem + 20992);

    const int t   = threadIdx.x;
    const int bid = blockIdx.x;
    const int b   = bid & 7;            // image <-> XCD affinity
    const int rem = bid >> 3;
    const int ho  = rem >> 1;
    const int wo0 = (rem & 1) << 6;
    const int l   = t & 63;
    const int wv  = __builtin_amdgcn_readfirstlane(t >> 6);

    // ---- per-(tap,pixel) metadata ----
    for (int i = t; i < 9 * 64; i += 256) {
        int p = i & 63;
        int k = i >> 6;
        int wo = wo0 + p;
        int obase = ((b * 18 + 2 * k) * HH + ho) * WW + wo;
        float oy = off[obase];
        float ox = off[obase + HW];
        float m  = msk[((b * 9 + k) * HH + ho) * WW + wo];
        float py = oy + (float)(k / 3) + (float)(ho - 1);
        float px = ox + (float)(k % 3) + (float)(wo - 1);
        float fy = floorf(py), fx = floorf(px);
        float ly = py - fy,    lx = px - fx;
        int y0 = (int)fy, x0 = (int)fx;
        int y1 = y0 + 1,  x1 = x0 + 1;
        float vy0 = (y0 >= 0 && y0 < HH) ? 1.f : 0.f;
        float vy1 = (y1 >= 0 && y1 < HH) ? 1.f : 0.f;
        float vx0 = (x0 >= 0 && x0 < WW) ? 1.f : 0.f;
        float vx1 = (x1 >= 0 && x1 < WW) ? 1.f : 0.f;
        float w00 = (1.f - ly) * (1.f - lx) * m * vy0 * vx0;
        float w01 = (1.f - ly) * lx         * m * vy0 * vx1;
        float w10 = ly         * (1.f - lx) * m * vy1 * vx0;
        float w11 = ly         * lx         * m * vy1 * vx1;
        int yc0 = min(max(y0, 0), HH - 1), yc1 = min(max(y1, 0), HH - 1);
        int xc0 = min(max(x0, 0), WW - 1), xc1 = min(max(x1, 0), WW - 1);
        moSu[i] = make_ushort4((unsigned short)(yc0 * WW + xc0),
                               (unsigned short)(yc0 * WW + xc1),
                               (unsigned short)(yc1 * WW + xc0),
                               (unsigned short)(yc1 * WW + xc1));
        __half2 hA = __floats2half2_rn(w00, w01);
        __half2 hB = __floats2half2_rn(w10, w11);
        mwH[i] = make_uint2(*(unsigned*)&hA, *(unsigned*)&hB);
    }

    const char* ib  = (const char*)xt + (size_t)b * HW * 128;  // image base (bytes)
    const int  pxg  = (wv << 4) + (l & 15);    // this lane's pixel (= A-frag row)
    const int  chq  = (l >> 4) << 4;           // byte offset of kf0 channel group

    __syncthreads();   // meta visible (only pre-epilogue barrier)

    f32x4 acc[4];
    #pragma unroll
    for (int g = 0; g < 4; ++g) acc[g] = (f32x4){0.f, 0.f, 0.f, 0.f};

    // packed-f16 combine: one 2-ch word = 3 hfma2 + 1 hmul2
    #define CMBH(dst_, c00, c01, c10, c11) {                         \
        __half2 a_ = __hmul2(*(__half2*)&(c11), W11);                \
        a_ = __hfma2(*(__half2*)&(c10), W10, a_);                    \
        a_ = __hfma2(*(__half2*)&(c01), W01, a_);                    \
        a_ = __hfma2(*(__half2*)&(c00), W00, a_);                    \
        dst_ = *(unsigned*)&a_;                                      \
    }

    // ---- 9 taps, zero barriers, pure register dataflow ----
    #pragma unroll
    for (int s = 0; s < 9; ++s) {
        ushort4 ob = moSu[s * 64 + pxg];
        uint2   wp = mwH[s * 64 + pxg];
        const char* p0 = ib + (((int)ob.x) << 7) + chq;
        const char* p1 = ib + (((int)ob.y) << 7) + chq;
        const char* p2 = ib + (((int)ob.z) << 7) + chq;
        const char* p3 = ib + (((int)ob.w) << 7) + chq;
        uint4 cA0 = *(const uint4*)p0;
        uint4 cA1 = *(const uint4*)p1;
        uint4 cA2 = *(const uint4*)p2;
        uint4 cA3 = *(const uint4*)p3;
        uint4 cB0 = *(const uint4*)(p0 + 64);
        uint4 cB1 = *(const uint4*)(p1 + 64);
        uint4 cB2 = *(const uint4*)(p2 + 64);
        uint4 cB3 = *(const uint4*)(p3 + 64);
        __half2 wab = *(__half2*)&wp.x, wcd = *(__half2*)&wp.y;
        __half2 W00 = __half2half2(__low2half(wab));
        __half2 W01 = __half2half2(__high2half(wab));
        __half2 W10 = __half2half2(__low2half(wcd));
        __half2 W11 = __half2half2(__high2half(wcd));
        uint4 u0, u1;
        CMBH(u0.x, cA0.x, cA1.x, cA2.x, cA3.x)
        CMBH(u0.y, cA0.y, cA1.y, cA2.y, cA3.y)
        CMBH(u0.z, cA0.z, cA1.z, cA2.z, cA3.z)
        CMBH(u0.w, cA0.w, cA1.w, cA2.w, cA3.w)
        CMBH(u1.x, cB0.x, cB1.x, cB2.x, cB3.x)
        CMBH(u1.y, cB0.y, cB1.y, cB2.y, cB3.y)
        CMBH(u1.z, cB0.z, cB1.z, cB2.z, cB3.z)
        CMBH(u1.w, cB0.w, cB1.w, cB2.w, cB3.w)
        half8 a0 = *(half8*)&u0;   // A-fragment, channels [0,32)
        half8 a1 = *(half8*)&u1;   // A-fragment, channels [32,64)
        #pragma unroll
        for (int cot = 0; cot < 4; ++cot) {
            short8 s0 = *(const short8*)(wt + (((s * 8 + cot)     * 64 + l) << 3));
            short8 s1 = *(const short8*)(wt + (((s * 8 + 4 + cot) * 64 + l) << 3));
            acc[cot] = __builtin_amdgcn_mfma_f32_16x16x32_f16(a0, *(half8*)&s0, acc[cot], 0, 0, 0);
            acc[cot] = __builtin_amdgcn_mfma_f32_16x16x32_f16(a1, *(half8*)&s1, acc[cot], 0, 0, 0);
        }
    }
    #undef CMBH

    // ---- epilogue: swizzled transpose through LDS (r14-verified mapping), coalesced stores ----
    float* out_t = (float*)smem;   // [64 co][256 B rows], XOR-swizzled
    const int pxb = (wv << 6) + ((l >> 4) << 4);   // byte col of this lane's 4-px group
    const int swE = (l & 15) << 4;                 // co_e & 15 == l & 15
    #pragma unroll
    for (int cot = 0; cot < 4; ++cot) {
        int co_e = (cot << 4) + (l & 15);
        float bv = bias[co_e];
        float4 v = make_float4(acc[cot][0] + bv, acc[cot][1] + bv,
                               acc[cot][2] + bv, acc[cot][3] + bv);
        *(float4*)((unsigned char*)out_t + co_e * 256 + (pxb ^ swE)) = v;
    }
    __syncthreads();
    float* outb = out + (size_t)b * 64 * HW + (size_t)ho * WW + wo0;
    #pragma unroll
    for (int j = 0; j < 4; ++j) {
        int co   = (t >> 4) + (j << 4);
        int colb = (t & 15) << 4;
        float4 v = *(const float4*)((const unsigned char*)out_t + co * 256 + (colb ^ ((co & 15) << 4)));
        *(float4*)&outb[(size_t)co * HW + ((t & 15) << 2)] = v;
    }
}

// -------- fallback (NCHW gather, raw weights, bf16 MFMA) for tiny workspace --------
__global__ __launch_bounds__(256, 4) void deform_fallback(
    const float* __restrict__ x, const float* __restrict__ off,
    const float* __restrict__ msk, const float* __restrict__ wraw,
    const float* __restrict__ bias, float* __restrict__ out)
{
    __shared__ unsigned short s_tile[2][64][68];
    __shared__ __align__(16) unsigned char meta_mem[18432];
    float4* mwS = (float4*)meta_mem;
    int4*   moS = (int4*)(meta_mem + 9216);
    float*  out_t = (float*)meta_mem;

    const int t   = threadIdx.x;
    const int bid = blockIdx.x;
    const int b   = bid & 7;
    const int rem = bid >> 3;
    const int ho  = rem >> 1;
    const int wo0 = (rem & 1) << 6;
    const int l   = t & 63;
    const int wv_id = __builtin_amdgcn_readfirstlane(t >> 6);
    const int c0  = wv_id << 4;
    const int cb  = wv_id << 4;

    short8 wtf[2][2];
    #pragma unroll
    for (int kf = 0; kf < 2; ++kf) {
        short8 f;
        int co = cb + (l & 15);
        int cbase = kf * 32 + (l >> 4) * 8;
        #pragma unroll
        for (int e = 0; e < 8; ++e) f[e] = (short)f2bf(wraw[(co * 64 + cbase + e) * 9 + 0]);
        wtf[0][kf] = f;
    }

    for (int i = t; i < 9 * 64; i += 256) {
        int p = i & 63;
        int k = i >> 6;
        int wo = wo0 + p;
        int obase = ((b * 18 + 2 * k) * HH + ho) * WW + wo;
        float oy = off[obase];
        float ox = off[obase + HW];
        float m  = msk[((b * 9 + k) * HH + ho) * WW + wo];
        float py = oy + (float)(k / 3) + (float)(ho - 1);
        float px = ox + (float)(k % 3) + (float)(wo - 1);
        float fy = floorf(py), fx = floorf(px);
        float ly = py - fy,    lx = px - fx;
        int y0 = (int)fy, x0 = (int)fx;
        int y1 = y0 + 1,  x1 = x0 + 1;
        float vy0 = (y0 >= 0 && y0 < HH) ? 1.f : 0.f;
        float vy1 = (y1 >= 0 && y1 < HH) ? 1.f : 0.f;
        float vx0 = (x0 >= 0 && x0 < WW) ? 1.f : 0.f;
        float vx1 = (x1 >= 0 && x1 < WW) ? 1.f : 0.f;
        float w00 = (1.f - ly) * (1.f - lx) * m * vy0 * vx0;
        float w01 = (1.f - ly) * lx         * m * vy0 * vx1;
        float w10 = ly         * (1.f - lx) * m * vy1 * vx0;
        float w11 = ly         * lx         * m * vy1 * vx1;
        int yc0 = min(max(y0, 0), HH - 1), yc1 = min(max(y1, 0), HH - 1);
        int xc0 = min(max(x0, 0), WW - 1), xc1 = min(max(x1, 0), WW - 1);
        mwS[i] = make_float4(w00, w01, w10, w11);
        moS[i] = make_int4(yc0 * WW + xc0, yc0 * WW + xc1,
                           yc1 * WW + xc0, yc1 * WW + xc1);
    }

    const int p = t & 63;
    const float* xb = x + (size_t)(b * 64 + c0) * HW;
    __syncthreads();

    {
        float4 wv = mwS[p];
        int4   ov = moS[p];
        const float* pc = xb;
        #pragma unroll
        for (int i = 0; i < 16; i += 4) {
            float v0 = wv.x * pc[ov.x] + wv.y * pc[ov.y] + wv.z * pc[ov.z] + wv.w * pc[ov.w]; pc += HW;
            float v1 = wv.x * pc[ov.x] + wv.y * pc[ov.y] + wv.z * pc[ov.z] + wv.w * pc[ov.w]; pc += HW;
            float v2 = wv.x * pc[ov.x] + wv.y * pc[ov.y] + wv.z * pc[ov.z] + wv.w * pc[ov.w]; pc += HW;
            float v3 = wv.x * pc[ov.x] + wv.y * pc[ov.y] + wv.z * pc[ov.z] + wv.w * pc[ov.w]; pc += HW;
            uint2 u;
            u.x = (unsigned)f2bf(v0) | ((unsigned)f2bf(v1) << 16);
            u.y = (unsigned)f2bf(v2) | ((unsigned)f2bf(v3) << 16);
            *(uint2*)&s_tile[0][p][c0 + i] = u;
        }
    }
    __syncthreads();

    f32x4 acc[4];
    #pragma unroll
    for (int g = 0; g < 4; ++g) acc[g] = (f32x4){0.f, 0.f, 0.f, 0.f};

    #pragma unroll
    for (int s = 0; s < 9; ++s) {
        if (s < 8) {
            const int kn = s + 1;
            #pragma unroll
            for (int kf = 0; kf < 2; ++kf) {
                short8 f;
                int co = cb + (l & 15);
                int cbase = kf * 32 + (l >> 4) * 8;
                #pragma unroll
                for (int e = 0; e < 8; ++e) f[e] = (short)f2bf(wraw[(co * 64 + cbase + e) * 9 + kn]);
                wtf[kn & 1][kf] = f;
            }
            float4 wv = mwS[kn * 64 + p];
            int4   ov = moS[kn * 64 + p];
            const float* pc = xb;
            #pragma unroll
            for (int i = 0; i < 16; i += 4) {
                float v0 = wv.x * pc[ov.x] + wv.y * pc[ov.y] + wv.z * pc[ov.z] + wv.w * pc[ov.w]; pc += HW;
                float v1 = wv.x * pc[ov.x] + wv.y * pc[ov.y] + wv.z * pc[ov.z] + wv.w * pc[ov.w]; pc += HW;
                float v2 = wv.x * pc[ov.x] + wv.y * pc[ov.y] + wv.z * pc[ov.z] + wv.w * pc[ov.w]; pc += HW;
                float v3 = wv.x * pc[ov.x] + wv.y * pc[ov.y] + wv.z * pc[ov.z] + wv.w * pc[ov.w]; pc += HW;
                uint2 u;
                u.x = (unsigned)f2bf(v0) | ((unsigned)f2bf(v1) << 16);
                u.y = (unsigned)f2bf(v2) | ((unsigned)f2bf(v3) << 16);
                *(uint2*)&s_tile[kn & 1][p][c0 + i] = u;
            }
        }
        #pragma unroll
        for (int g = 0; g < 4; ++g) {
            const int prow = g * 16 + (l & 15);
            const unsigned short* rp = &s_tile[s & 1][prow][(l >> 4) * 8];
            union { short8 v; unsigned long long q[2]; } ua0, ua1;
            ua0.q[0] = *(const unsigned long long*)(rp);
            ua0.q[1] = *(const unsigned long long*)(rp + 4);
            ua1.q[0] = *(const unsigned long long*)(rp + 32);
            ua1.q[1] = *(const unsigned long long*)(rp + 36);
            acc[g] = __builtin_amdgcn_mfma_f32_16x16x32_bf16(ua0.v, wtf[s & 1][0], acc[g], 0, 0, 0);
            acc[g] = __builtin_amdgcn_mfma_f32_16x16x32_bf16(ua1.v, wtf[s & 1][1], acc[g], 0, 0, 0);
        }
        __syncthreads();
    }

    const float bv = bias[cb + (l & 15)];
    #pragma unroll
    for (int g = 0; g < 4; ++g) {
        int co = cb + (l & 15);
        int pxb = g * 16 + (l >> 4) * 4;
        #pragma unroll
        for (int r = 0; r < 4; ++r)
            out_t[co * 68 + pxb + r] = acc[g][r] + bv;
    }
    __syncthreads();
    float* outb = out + (size_t)b * 64 * HW + (size_t)ho * WW + wo0;
    #pragma unroll
    for (int j = 0; j < 4; ++j) {
        int co  = (t >> 4) + j * 16;
        int px0 = (t & 15) << 2;
        float4 v = *(float4*)&out_t[co * 68 + px0];
        *(float4*)&outb[(size_t)co * HW + px0] = v;
    }
}

extern "C" void kernel_launch(void* const* d_in, const int* in_sizes, int n_in,
                              void* d_out, int out_size, void* d_ws, size_t ws_size,
                              hipStream_t stream) {
    const float* x    = (const float*)d_in[0];
    const float* off  = (const float*)d_in[1];
    const float* msk  = (const float*)d_in[2];
    const float* w    = (const float*)d_in[3];
    const float* bias = (const float*)d_in[4];
    float* out = (float*)d_out;

    const size_t need = XT_BYTES + WT_BYTES;
    if (d_ws != nullptr && ws_size >= need) {
        unsigned int*   xt32 = (unsigned int*)d_ws;
        unsigned short* wt   = (unsigned short*)((char*)d_ws + XT_BYTES);
        xtrans_kernel<<<2048, 256, 0, stream>>>(x, xt32);
        wtrans_kernel<<<144, 256, 0, stream>>>(w, wt);
        deform_nhwc<<<2048, 256, 0, stream>>>((const unsigned short*)xt32, off, msk, wt, bias, out);
    } else {
        deform_fallback<<<2048, 256, 0, stream>>>(x, off, msk, w, bias, out);
    }
}

// Round 17
// 49.047 us; speedup vs baseline: 2.0075x; 2.0075x over previous
//
#include <hip/hip_runtime.h>
#include <hip/hip_fp16.h>

#define HH 128
#define WW 128
#define HW (HH*WW)
#define XT_BYTES ((size_t)8 * HW * 64 * 2)   // x_t f16 NHWC
#define WT_BYTES ((size_t)9 * 2 * 4 * 64 * 8 * 2)

typedef __attribute__((ext_vector_type(8))) short short8;
typedef __attribute__((ext_vector_type(4))) float f32x4;
typedef _Float16 half8 __attribute__((ext_vector_type(8)));

static __device__ __forceinline__ unsigned short f2bf(float f) {
    unsigned int u = __float_as_uint(f);
    u += 0x7fffu + ((u >> 16) & 1u);
    return (unsigned short)(u >> 16);
}
static __device__ __forceinline__ unsigned pkrtz(float lo, float hi) {
    auto r = __builtin_amdgcn_cvt_pkrtz(lo, hi);   // __fp16 ext_vector(2)
    return *(unsigned*)&r;
}

// weight (64,64,3,3) fp32 -> f16 B-fragment layout wt[tap][kf][wave][lane][e]
__global__ void wtrans_kernel(const float* __restrict__ w, unsigned short* __restrict__ wt) {
    int i = blockIdx.x * 256 + threadIdx.x;
    if (i < 9 * 2 * 4 * 64 * 8) {
        int e  = i & 7;
        int l  = (i >> 3) & 63;
        int wv = (i >> 9) & 3;
        int kf = (i >> 11) & 1;
        int k  = i >> 12;
        int co = wv * 16 + (l & 15);
        int c  = kf * 32 + (l >> 4) * 8 + e;
        __half hh = __float2half_rn(w[(co * 64 + c) * 9 + k]);
        wt[i] = __half_as_ushort(hh);
    }
}

// x [8,64,128,128] f32 -> x_t [8,HW,64] f16 (NHWC). Block: 64 hw x 64 ch.
__global__ __launch_bounds__(256) void xtrans_kernel(const float* __restrict__ x,
                                                     unsigned int* __restrict__ xt32) {
    __shared__ float tile[64][65];
    const int bid = blockIdx.x;
    const int b   = bid >> 8;
    const int hw0 = (bid & 255) << 6;
    const int t   = threadIdx.x;
    #pragma unroll
    for (int i = 0; i < 16; ++i) {
        int idx = (i << 8) + t;
        int c = idx >> 6, j = idx & 63;
        tile[c][j] = x[(size_t)(((b << 6) + c) << 14) + hw0 + j];
    }
    __syncthreads();
    #pragma unroll
    for (int i = 0; i < 8; ++i) {
        int idx = (i << 8) + t;
        int cp = idx & 31, hw = idx >> 5;
        xt32[((size_t)((b << 14) + hw0 + hw) << 5) + cp] =
            pkrtz(tile[2 * cp][hw], tile[2 * cp + 1][hw]);
    }
}

// Fast path: block = 64 px (half row), 4 waves; wave wv: px [16wv,16wv+16) sampling + couts [16wv,16wv+16) MFMA.
// r13 structure with 2 TAPS PER BARRIER INTERVAL: 5 main-loop barriers instead of 9.
// Tap k lives at buf[(k>>1)&1] + (k&1)*8KB.
__global__ __launch_bounds__(256, 3) void deform_nhwc(
    const unsigned short* __restrict__ xt,  // [8][HW][64] f16
    const float* __restrict__ off,
    const float* __restrict__ msk,
    const unsigned short* __restrict__ wt,  // packed f16 B-fragments
    const float* __restrict__ bias,
    float* __restrict__ out)
{
    // [0,32768): two 16 KB stage buffers (each = 2 taps x [64px][128B], XOR-swizzled)
    // [32768,37376): moSu ushort4 corner hw-indices [9*64]  (byte off = idx<<7)
    // [37376,41984): mwH uint2 packed fp16 weight pairs [9*64]
    // epilogue: [0,16384) reused as swizzled fp32 out_t
    __shared__ __align__(16) unsigned char smem[41984];
    ushort4* moSu = (ushort4*)(smem + 32768);
    uint2*   mwH  = (uint2*)(smem + 37376);

    const int t   = threadIdx.x;
    const int bid = blockIdx.x;
    const int b   = bid & 7;            // image <-> XCD affinity
    const int rem = bid >> 3;
    const int ho  = rem >> 1;
    const int wo0 = (rem & 1) << 6;
    const int l   = t & 63;
    const int wv  = __builtin_amdgcn_readfirstlane(t >> 6);

    // ---- per-(tap,pixel) metadata ----
    for (int i = t; i < 9 * 64; i += 256) {
        int p = i & 63;
        int k = i >> 6;
        int wo = wo0 + p;
        int obase = ((b * 18 + 2 * k) * HH + ho) * WW + wo;
        float oy = off[obase];
        float ox = off[obase + HW];
        float m  = msk[((b * 9 + k) * HH + ho) * WW + wo];
        float py = oy + (float)(k / 3) + (float)(ho - 1);
        float px = ox + (float)(k % 3) + (float)(wo - 1);
        float fy = floorf(py), fx = floorf(px);
        float ly = py - fy,    lx = px - fx;
        int y0 = (int)fy, x0 = (int)fx;
        int y1 = y0 + 1,  x1 = x0 + 1;
        float vy0 = (y0 >= 0 && y0 < HH) ? 1.f : 0.f;
        float vy1 = (y1 >= 0 && y1 < HH) ? 1.f : 0.f;
        float vx0 = (x0 >= 0 && x0 < WW) ? 1.f : 0.f;
        float vx1 = (x1 >= 0 && x1 < WW) ? 1.f : 0.f;
        float w00 = (1.f - ly) * (1.f - lx) * m * vy0 * vx0;
        float w01 = (1.f - ly) * lx         * m * vy0 * vx1;
        float w10 = ly         * (1.f - lx) * m * vy1 * vx0;
        float w11 = ly         * lx         * m * vy1 * vx1;
        int yc0 = min(max(y0, 0), HH - 1), yc1 = min(max(y1, 0), HH - 1);
        int xc0 = min(max(x0, 0), WW - 1), xc1 = min(max(x1, 0), WW - 1);
        moSu[i] = make_ushort4((unsigned short)(yc0 * WW + xc0),
                               (unsigned short)(yc0 * WW + xc1),
                               (unsigned short)(yc1 * WW + xc0),
                               (unsigned short)(yc1 * WW + xc1));
        __half2 hA = __floats2half2_rn(w00, w01);
        __half2 hB = __floats2half2_rn(w10, w11);
        mwH[i] = make_uint2(*(unsigned*)&hA, *(unsigned*)&hB);
    }

    const char* ib   = (const char*)xt + (size_t)b * HW * 128;  // image base (bytes)
    const int  chb   = (l & 7) << 4;               // byte offset of this lane's 8 channels
    const int  px0_  = (wv << 4) + (l >> 3);       // r=0 pixel
    int st_woff[2];
    st_woff[0] = px0_ * 128 + (chb ^ ((px0_ & 7) << 4));
    st_woff[1] = st_woff[0] + 8 * 128;             // (px0_+8)&7 == px0_&7
    const int lq = (l >> 4) << 4;                  // fragment k-group byte base
    const int sw = (l & 7) << 4;                   // read-side swizzle (prow&7 == l&7)

    uint4 gA[8], gB[8];    // in-flight gathers for the 2 taps of the next stage
    half8 wtf[2][2][2];    // [stage parity][tap parity][kf]

    #define ISSUE_TAP(kk, A) {                                       \
        ushort4 ob0 = moSu[(kk) * 64 + px0_];                        \
        A[0] = *(const uint4*)(ib + (((int)ob0.x) << 7) + chb);      \
        A[1] = *(const uint4*)(ib + (((int)ob0.y) << 7) + chb);      \
        A[2] = *(const uint4*)(ib + (((int)ob0.z) << 7) + chb);      \
        A[3] = *(const uint4*)(ib + (((int)ob0.w) << 7) + chb);      \
        ushort4 ob1 = moSu[(kk) * 64 + px0_ + 8];                    \
        A[4] = *(const uint4*)(ib + (((int)ob1.x) << 7) + chb);      \
        A[5] = *(const uint4*)(ib + (((int)ob1.y) << 7) + chb);      \
        A[6] = *(const uint4*)(ib + (((int)ob1.z) << 7) + chb);      \
        A[7] = *(const uint4*)(ib + (((int)ob1.w) << 7) + chb);      \
    }

    #define WTFLD(kk, sp) {                                          \
        _Pragma("unroll")                                            \
        for (int kf = 0; kf < 2; ++kf) {                             \
            short8 sv = *(const short8*)(wt + ((((kk) * 2 + kf) * 4 + wv) * 64 + l) * 8); \
            wtf[sp][(kk) & 1][kf] = *(half8*)&sv;                    \
        }                                                            \
    }

    // packed-f16 combine: one 2-ch word = 3 hfma2 + 1 hmul2
    #define CMBH(dst_, c00, c01, c10, c11) {                         \
        __half2 a_ = __hmul2(*(__half2*)&(c11), W11);                \
        a_ = __hfma2(*(__half2*)&(c10), W10, a_);                    \
        a_ = __hfma2(*(__half2*)&(c01), W01, a_);                    \
        a_ = __hfma2(*(__half2*)&(c00), W00, a_);                    \
        dst_ = *(unsigned*)&a_;                                      \
    }

    #define COMBINE_STORE(kk, A, dstb) {                             \
        {                                                            \
            uint2 wp = mwH[(kk) * 64 + px0_];                        \
            __half2 wab = *(__half2*)&wp.x, wcd = *(__half2*)&wp.y;  \
            __half2 W00 = __half2half2(__low2half(wab));             \
            __half2 W01 = __half2half2(__high2half(wab));            \
            __half2 W10 = __half2half2(__low2half(wcd));             \
            __half2 W11 = __half2half2(__high2half(wcd));            \
            uint4 uv;                                                \
            CMBH(uv.x, A[0].x, A[1].x, A[2].x, A[3].x)               \
            CMBH(uv.y, A[0].y, A[1].y, A[2].y, A[3].y)               \
            CMBH(uv.z, A[0].z, A[1].z, A[2].z, A[3].z)               \
            CMBH(uv.w, A[0].w, A[1].w, A[2].w, A[3].w)               \
            *(uint4*)((dstb) + st_woff[0]) = uv;                     \
        }                                                            \
        {                                                            \
            uint2 wp = mwH[(kk) * 64 + px0_ + 8];                    \
            __half2 wab = *(__half2*)&wp.x, wcd = *(__half2*)&wp.y;  \
            __half2 W00 = __half2half2(__low2half(wab));             \
            __half2 W01 = __half2half2(__high2half(wab));            \
            __half2 W10 = __half2half2(__low2half(wcd));             \
            __half2 W11 = __half2half2(__high2half(wcd));            \
            uint4 uv;                                                \
            CMBH(uv.x, A[4].x, A[5].x, A[6].x, A[7].x)               \
            CMBH(uv.y, A[4].y, A[5].y, A[6].y, A[7].y)               \
            CMBH(uv.z, A[4].z, A[5].z, A[6].z, A[7].z)               \
            CMBH(uv.w, A[4].w, A[5].w, A[6].w, A[7].w)               \
            *(uint4*)((dstb) + st_woff[1]) = uv;                     \
        }                                                            \
    }

    __syncthreads();   // meta visible

    // ---- prologue: taps 0,1 -> buf0 ----
    ISSUE_TAP(0, gA)
    ISSUE_TAP(1, gB)
    WTFLD(0, 0)
    WTFLD(1, 0)
    COMBINE_STORE(0, gA, smem)
    COMBINE_STORE(1, gB, smem + 8192)
    __syncthreads();

    f32x4 acc[4];
    #pragma unroll
    for (int g = 0; g < 4; ++g) acc[g] = (f32x4){0.f, 0.f, 0.f, 0.f};

    // ---- 4 stages of 2 taps + 1 tail stage ----
    #pragma unroll
    for (int st = 0; st < 4; ++st) {
        // issue next-stage gathers + wtf
        if (st < 3) {
            ISSUE_TAP(2 * st + 2, gA)
            ISSUE_TAP(2 * st + 3, gB)
            WTFLD(2 * st + 2, (st + 1) & 1)
            WTFLD(2 * st + 3, (st + 1) & 1)
        } else {
            ISSUE_TAP(8, gA)
            WTFLD(8, (st + 1) & 1)
        }
        __builtin_amdgcn_sched_barrier(0);   // issues stay above
        {
            const unsigned char* rb = smem + ((st & 1) << 14);
            #pragma unroll
            for (int g = 0; g < 4; ++g) {
                const int prow = g * 16 + (l & 15);
                short8 a00 = *(const short8*)(rb + prow * 128 + (lq ^ sw));
                short8 a01 = *(const short8*)(rb + prow * 128 + ((64 + lq) ^ sw));
                short8 a10 = *(const short8*)(rb + 8192 + prow * 128 + (lq ^ sw));
                short8 a11 = *(const short8*)(rb + 8192 + prow * 128 + ((64 + lq) ^ sw));
                acc[g] = __builtin_amdgcn_mfma_f32_16x16x32_f16(*(half8*)&a00, wtf[st & 1][0][0], acc[g], 0, 0, 0);
                acc[g] = __builtin_amdgcn_mfma_f32_16x16x32_f16(*(half8*)&a01, wtf[st & 1][0][1], acc[g], 0, 0, 0);
                acc[g] = __builtin_amdgcn_mfma_f32_16x16x32_f16(*(half8*)&a10, wtf[st & 1][1][0], acc[g], 0, 0, 0);
                acc[g] = __builtin_amdgcn_mfma_f32_16x16x32_f16(*(half8*)&a11, wtf[st & 1][1][1], acc[g], 0, 0, 0);
            }
        }
        __builtin_amdgcn_sched_barrier(0);   // vmem drain lands after MFMAs
        {
            unsigned char* wb = smem + (((st + 1) & 1) << 14);
            if (st < 3) {
                COMBINE_STORE(2 * st + 2, gA, wb)
                COMBINE_STORE(2 * st + 3, gB, wb + 8192)
            } else {
                COMBINE_STORE(8, gA, wb)
            }
        }
        __syncthreads();
    }
    // ---- tail stage: tap 8 (buf0 sub0) ----
    {
        const unsigned char* rb = smem;
        #pragma unroll
        for (int g = 0; g < 4; ++g) {
            const int prow = g * 16 + (l & 15);
            short8 a00 = *(const short8*)(rb + prow * 128 + (lq ^ sw));
            short8 a01 = *(const short8*)(rb + prow * 128 + ((64 + lq) ^ sw));
            acc[g] = __builtin_amdgcn_mfma_f32_16x16x32_f16(*(half8*)&a00, wtf[0][0][0], acc[g], 0, 0, 0);
            acc[g] = __builtin_amdgcn_mfma_f32_16x16x32_f16(*(half8*)&a01, wtf[0][0][1], acc[g], 0, 0, 0);
        }
    }
    #undef ISSUE_TAP
    #undef WTFLD
    #undef CMBH
    #undef COMBINE_STORE

    __syncthreads();   // all waves done reading tap 8 before out_t overlay

    // ---- epilogue: swizzled transpose through LDS, coalesced float4 stores ----
    float* out_t = (float*)smem;   // [64 co][256 B rows], XOR-swizzled
    const int cb = wv << 4;
    const int co_e = cb + (l & 15);
    const float bv = bias[co_e];
    const int swE = (co_e & 15) << 4;
    #pragma unroll
    for (int g = 0; g < 4; ++g) {
        int pxb = (g << 6) + ((l >> 4) << 4);   // byte col of pixel group
        float4 v = make_float4(acc[g][0] + bv, acc[g][1] + bv, acc[g][2] + bv, acc[g][3] + bv);
        *(float4*)((unsigned char*)out_t + co_e * 256 + (pxb ^ swE)) = v;
    }
    __syncthreads();
    float* outb = out + (size_t)b * 64 * HW + (size_t)ho * WW + wo0;
    #pragma unroll
    for (int j = 0; j < 4; ++j) {
        int co   = (t >> 4) + (j << 4);
        int colb = (t & 15) << 4;
        float4 v = *(const float4*)((const unsigned char*)out_t + co * 256 + (colb ^ ((co & 15) << 4)));
        *(float4*)&outb[(size_t)co * HW + ((t & 15) << 2)] = v;
    }
}

// -------- fallback (NCHW gather, raw weights, bf16 MFMA) for tiny workspace --------
__global__ __launch_bounds__(256, 4) void deform_fallback(
    const float* __restrict__ x, const float* __restrict__ off,
    const float* __restrict__ msk, const float* __restrict__ wraw,
    const float* __restrict__ bias, float* __restrict__ out)
{
    __shared__ unsigned short s_tile[2][64][68];
    __shared__ __align__(16) unsigned char meta_mem[18432];
    float4* mwS = (float4*)meta_mem;
    int4*   moS = (int4*)(meta_mem + 9216);
    float*  out_t = (float*)meta_mem;

    const int t   = threadIdx.x;
    const int bid = blockIdx.x;
    const int b   = bid & 7;
    const int rem = bid >> 3;
    const int ho  = rem >> 1;
    const int wo0 = (rem & 1) << 6;
    const int l   = t & 63;
    const int wv_id = __builtin_amdgcn_readfirstlane(t >> 6);
    const int c0  = wv_id << 4;
    const int cb  = wv_id << 4;

    short8 wtf[2][2];
    #pragma unroll
    for (int kf = 0; kf < 2; ++kf) {
        short8 f;
        int co = cb + (l & 15);
        int cbase = kf * 32 + (l >> 4) * 8;
        #pragma unroll
        for (int e = 0; e < 8; ++e) f[e] = (short)f2bf(wraw[(co * 64 + cbase + e) * 9 + 0]);
        wtf[0][kf] = f;
    }

    for (int i = t; i < 9 * 64; i += 256) {
        int p = i & 63;
        int k = i >> 6;
        int wo = wo0 + p;
        int obase = ((b * 18 + 2 * k) * HH + ho) * WW + wo;
        float oy = off[obase];
        float ox = off[obase + HW];
        float m  = msk[((b * 9 + k) * HH + ho) * WW + wo];
        float py = oy + (float)(k / 3) + (float)(ho - 1);
        float px = ox + (float)(k % 3) + (float)(wo - 1);
        float fy = floorf(py), fx = floorf(px);
        float ly = py - fy,    lx = px - fx;
        int y0 = (int)fy, x0 = (int)fx;
        int y1 = y0 + 1,  x1 = x0 + 1;
        float vy0 = (y0 >= 0 && y0 < HH) ? 1.f : 0.f;
        float vy1 = (y1 >= 0 && y1 < HH) ? 1.f : 0.f;
        float vx0 = (x0 >= 0 && x0 < WW) ? 1.f : 0.f;
        float vx1 = (x1 >= 0 && x1 < WW) ? 1.f : 0.f;
        float w00 = (1.f - ly) * (1.f - lx) * m * vy0 * vx0;
        float w01 = (1.f - ly) * lx         * m * vy0 * vx1;
        float w10 = ly         * (1.f - lx) * m * vy1 * vx0;
        float w11 = ly         * lx         * m * vy1 * vx1;
        int yc0 = min(max(y0, 0), HH - 1), yc1 = min(max(y1, 0), HH - 1);
        int xc0 = min(max(x0, 0), WW - 1), xc1 = min(max(x1, 0), WW - 1);
        mwS[i] = make_float4(w00, w01, w10, w11);
        moS[i] = make_int4(yc0 * WW + xc0, yc0 * WW + xc1,
                           yc1 * WW + xc0, yc1 * WW + xc1);
    }

    const int p = t & 63;
    const float* xb = x + (size_t)(b * 64 + c0) * HW;
    __syncthreads();

    {
        float4 wv = mwS[p];
        int4   ov = moS[p];
        const float* pc = xb;
        #pragma unroll
        for (int i = 0; i < 16; i += 4) {
            float v0 = wv.x * pc[ov.x] + wv.y * pc[ov.y] + wv.z * pc[ov.z] + wv.w * pc[ov.w]; pc += HW;
            float v1 = wv.x * pc[ov.x] + wv.y * pc[ov.y] + wv.z * pc[ov.z] + wv.w * pc[ov.w]; pc += HW;
            float v2 = wv.x * pc[ov.x] + wv.y * pc[ov.y] + wv.z * pc[ov.z] + wv.w * pc[ov.w]; pc += HW;
            float v3 = wv.x * pc[ov.x] + wv.y * pc[ov.y] + wv.z * pc[ov.z] + wv.w * pc[ov.w]; pc += HW;
            uint2 u;
            u.x = (unsigned)f2bf(v0) | ((unsigned)f2bf(v1) << 16);
            u.y = (unsigned)f2bf(v2) | ((unsigned)f2bf(v3) << 16);
            *(uint2*)&s_tile[0][p][c0 + i] = u;
        }
    }
    __syncthreads();

    f32x4 acc[4];
    #pragma unroll
    for (int g = 0; g < 4; ++g) acc[g] = (f32x4){0.f, 0.f, 0.f, 0.f};

    #pragma unroll
    for (int s = 0; s < 9; ++s) {
        if (s < 8) {
            const int kn = s + 1;
            #pragma unroll
            for (int kf = 0; kf < 2; ++kf) {
                short8 f;
                int co = cb + (l & 15);
                int cbase = kf * 32 + (l >> 4) * 8;
                #pragma unroll
                for (int e = 0; e < 8; ++e) f[e] = (short)f2bf(wraw[(co * 64 + cbase + e) * 9 + kn]);
                wtf[kn & 1][kf] = f;
            }
            float4 wv = mwS[kn * 64 + p];
            int4   ov = moS[kn * 64 + p];
            const float* pc = xb;
            #pragma unroll
            for (int i = 0; i < 16; i += 4) {
                float v0 = wv.x * pc[ov.x] + wv.y * pc[ov.y] + wv.z * pc[ov.z] + wv.w * pc[ov.w]; pc += HW;
                float v1 = wv.x * pc[ov.x] + wv.y * pc[ov.y] + wv.z * pc[ov.z] + wv.w * pc[ov.w]; pc += HW;
                float v2 = wv.x * pc[ov.x] + wv.y * pc[ov.y] + wv.z * pc[ov.z] + wv.w * pc[ov.w]; pc += HW;
                float v3 = wv.x * pc[ov.x] + wv.y * pc[ov.y] + wv.z * pc[ov.z] + wv.w * pc[ov.w]; pc += HW;
                uint2 u;
                u.x = (unsigned)f2bf(v0) | ((unsigned)f2bf(v1) << 16);
                u.y = (unsigned)f2bf(v2) | ((unsigned)f2bf(v3) << 16);
                *(uint2*)&s_tile[kn & 1][p][c0 + i] = u;
            }
        }
        #pragma unroll
        for (int g = 0; g < 4; ++g) {
            const int prow = g * 16 + (l & 15);
            const unsigned short* rp = &s_tile[s & 1][prow][(l >> 4) * 8];
            union { short8 v; unsigned long long q[2]; } ua0, ua1;
            ua0.q[0] = *(const unsigned long long*)(rp);
            ua0.q[1] = *(const unsigned long long*)(rp + 4);
            ua1.q[0] = *(const unsigned long long*)(rp + 32);
            ua1.q[1] = *(const unsigned long long*)(rp + 36);
            acc[g] = __builtin_amdgcn_mfma_f32_16x16x32_bf16(ua0.v, wtf[s & 1][0], acc[g], 0, 0, 0);
            acc[g] = __builtin_amdgcn_mfma_f32_16x16x32_bf16(ua1.v, wtf[s & 1][1], acc[g], 0, 0, 0);
        }
        __syncthreads();
    }

    const float bv = bias[cb + (l & 15)];
    #pragma unroll
    for (int g = 0; g < 4; ++g) {
        int co = cb + (l & 15);
        int pxb = g * 16 + (l >> 4) * 4;
        #pragma unroll
        for (int r = 0; r < 4; ++r)
            out_t[co * 68 + pxb + r] = acc[g][r] + bv;
    }
    __syncthreads();
    float* outb = out + (size_t)b * 64 * HW + (size_t)ho * WW + wo0;
    #pragma unroll
    for (int j = 0; j < 4; ++j) {
        int co  = (t >> 4) + j * 16;
        int px0 = (t & 15) << 2;
        float4 v = *(float4*)&out_t[co * 68 + px0];
        *(float4*)&outb[(size_t)co * HW + px0] = v;
    }
}

extern "C" void kernel_launch(void* const* d_in, const int* in_sizes, int n_in,
                              void* d_out, int out_size, void* d_ws, size_t ws_size,
                              hipStream_t stream) {
    const float* x    = (const float*)d_in[0];
    const float* off  = (const float*)d_in[1];
    const float* msk  = (const float*)d_in[2];
    const float* w    = (const float*)d_in[3];
    const float* bias = (const float*)d_in[4];
    float* out = (float*)d_out;

    const size_t need = XT_BYTES + WT_BYTES;
    if (d_ws != nullptr && ws_size >= need) {
        unsigned int*   xt32 = (unsigned int*)d_ws;
        unsigned short* wt   = (unsigned short*)((char*)d_ws + XT_BYTES);
        xtrans_kernel<<<2048, 256, 0, stream>>>(x, xt32);
        wtrans_kernel<<<144, 256, 0, stream>>>(w, wt);
        deform_nhwc<<<2048, 256, 0, stream>>>((const unsigned short*)xt32, off, msk, wt, bias, out);
    } else {
        deform_fallback<<<2048, 256, 0, stream>>>(x, off, msk, w, bias, out);
    }
}

// Round 18
// 47.236 us; speedup vs baseline: 2.0845x; 1.0383x over previous
//
#include <hip/hip_runtime.h>
#include <hip/hip_fp16.h>

#define HH 128
#define WW 128
#define HW (HH*WW)
#define XT_BYTES ((size_t)8 * HW * 64 * 2)   // x_t f16 NHWC
#define WT_BYTES ((size_t)9 * 2 * 4 * 64 * 8 * 2)

typedef __attribute__((ext_vector_type(8))) short short8;
typedef __attribute__((ext_vector_type(4))) float f32x4;
typedef _Float16 half8 __attribute__((ext_vector_type(8)));

static __device__ __forceinline__ unsigned short f2bf(float f) {
    unsigned int u = __float_as_uint(f);
    u += 0x7fffu + ((u >> 16) & 1u);
    return (unsigned short)(u >> 16);
}
static __device__ __forceinline__ unsigned pkrtz(float lo, float hi) {
    auto r = __builtin_amdgcn_cvt_pkrtz(lo, hi);   // __fp16 ext_vector(2)
    return *(unsigned*)&r;
}

// weight (64,64,3,3) fp32 -> f16 B-fragment layout wt[tap][kf][wave][lane][e]
__global__ void wtrans_kernel(const float* __restrict__ w, unsigned short* __restrict__ wt) {
    int i = blockIdx.x * 256 + threadIdx.x;
    if (i < 9 * 2 * 4 * 64 * 8) {
        int e  = i & 7;
        int l  = (i >> 3) & 63;
        int wv = (i >> 9) & 3;
        int kf = (i >> 11) & 1;
        int k  = i >> 12;
        int co = wv * 16 + (l & 15);
        int c  = kf * 32 + (l >> 4) * 8 + e;
        __half hh = __float2half_rn(w[(co * 64 + c) * 9 + k]);
        wt[i] = __half_as_ushort(hh);
    }
}

// x [8,64,128,128] f32 -> x_t [8,HW,64] f16 (NHWC). Block: 64 hw x 64 ch.
__global__ __launch_bounds__(256) void xtrans_kernel(const float* __restrict__ x,
                                                     unsigned int* __restrict__ xt32) {
    __shared__ float tile[64][65];
    const int bid = blockIdx.x;
    const int b   = bid >> 8;
    const int hw0 = (bid & 255) << 6;
    const int t   = threadIdx.x;
    #pragma unroll
    for (int i = 0; i < 16; ++i) {
        int idx = (i << 8) + t;
        int c = idx >> 6, j = idx & 63;
        tile[c][j] = x[(size_t)(((b << 6) + c) << 14) + hw0 + j];
    }
    __syncthreads();
    #pragma unroll
    for (int i = 0; i < 8; ++i) {
        int idx = (i << 8) + t;
        int cp = idx & 31, hw = idx >> 5;
        xt32[((size_t)((b << 14) + hw0 + hw) << 5) + cp] =
            pkrtz(tile[2 * cp][hw], tile[2 * cp + 1][hw]);
    }
}

// Fast path: block = 64 px (half row), 4 waves; wave w: px [16w,16w+16) sampling + couts [16w,16w+16) MFMA.
// r10 structure (best measured). Combine is packed-f16: 4 v_pk_fma_f16-class ops per 2-ch word,
// bilinear weights pre-broadcast as __half2 in LDS (zero unpack/pack VALU).
__global__ __launch_bounds__(256, 4) void deform_nhwc(
    const unsigned short* __restrict__ xt,  // [8][HW][64] f16
    const float* __restrict__ off,
    const float* __restrict__ msk,
    const unsigned short* __restrict__ wt,  // packed f16 B-fragments
    const float* __restrict__ bias,
    float* __restrict__ out)
{
    // [0,16384): two 8 KB sample buffers, XOR-swizzled [64 px][64 ch] f16
    // [16384,25600): moS int4 corner byte-offsets [9*64]
    // [25600,34816): mw4 uint4 = 4x broadcast __half2 bilinear weights [9*64]
    // epilogue: [0,16384) reused as swizzled fp32 out_t
    __shared__ __align__(16) unsigned char smem[34816];
    int4*  moS = (int4*)(smem + 16384);
    uint4* mw4 = (uint4*)(smem + 25600);

    const int t   = threadIdx.x;
    const int bid = blockIdx.x;
    const int b   = bid & 7;            // image <-> XCD affinity
    const int rem = bid >> 3;
    const int ho  = rem >> 1;
    const int wo0 = (rem & 1) << 6;
    const int l   = t & 63;
    const int wv  = __builtin_amdgcn_readfirstlane(t >> 6);

    // ---- per-(tap,pixel) metadata ----
    for (int i = t; i < 9 * 64; i += 256) {
        int p = i & 63;
        int k = i >> 6;
        int wo = wo0 + p;
        int obase = ((b * 18 + 2 * k) * HH + ho) * WW + wo;
        float oy = off[obase];
        float ox = off[obase + HW];
        float m  = msk[((b * 9 + k) * HH + ho) * WW + wo];
        float py = oy + (float)(k / 3) + (float)(ho - 1);
        float px = ox + (float)(k % 3) + (float)(wo - 1);
        float fy = floorf(py), fx = floorf(px);
        float ly = py - fy,    lx = px - fx;
        int y0 = (int)fy, x0 = (int)fx;
        int y1 = y0 + 1,  x1 = x0 + 1;
        float vy0 = (y0 >= 0 && y0 < HH) ? 1.f : 0.f;
        float vy1 = (y1 >= 0 && y1 < HH) ? 1.f : 0.f;
        float vx0 = (x0 >= 0 && x0 < WW) ? 1.f : 0.f;
        float vx1 = (x1 >= 0 && x1 < WW) ? 1.f : 0.f;
        float w00 = (1.f - ly) * (1.f - lx) * m * vy0 * vx0;
        float w01 = (1.f - ly) * lx         * m * vy0 * vx1;
        float w10 = ly         * (1.f - lx) * m * vy1 * vx0;
        float w11 = ly         * lx         * m * vy1 * vx1;
        int yc0 = min(max(y0, 0), HH - 1), yc1 = min(max(y1, 0), HH - 1);
        int xc0 = min(max(x0, 0), WW - 1), xc1 = min(max(x1, 0), WW - 1);
        moS[i] = make_int4((yc0 * WW + xc0) << 7, (yc0 * WW + xc1) << 7,
                           (yc1 * WW + xc0) << 7, (yc1 * WW + xc1) << 7);
        __half2 W00 = __half2half2(__float2half_rn(w00));
        __half2 W01 = __half2half2(__float2half_rn(w01));
        __half2 W10 = __half2half2(__float2half_rn(w10));
        __half2 W11 = __half2half2(__float2half_rn(w11));
        mw4[i] = make_uint4(*(unsigned*)&W00, *(unsigned*)&W01,
                            *(unsigned*)&W10, *(unsigned*)&W11);
    }

    const char* ib   = (const char*)xt + (size_t)b * HW * 128;  // image base (bytes)
    const int  chb   = (l & 7) << 4;               // byte offset of this lane's 8 channels
    const int  px0_  = (wv << 4) + (l >> 3);       // r=0 pixel
    int st_woff[2];
    st_woff[0] = px0_ * 128 + (chb ^ ((px0_ & 7) << 4));
    st_woff[1] = st_woff[0] + 8 * 128;             // (px0_+8)&7 == px0_&7
    const int lq = (l >> 4) << 4;                  // fragment col-byte base
    const int sw = (l & 7) << 4;                   // read-side swizzle (prow&7 == l&7)

    uint4 g0[4], g1[4];    // in-flight gathers: [corner] for r=0 / r=1 pixels
    half8 wtf[2][2];       // rotating B-fragments

    #define ISSUE_TAP(kk) {                                          \
        int4 ob0 = moS[(kk) * 64 + px0_];                            \
        g0[0] = *(const uint4*)(ib + ob0.x + chb);                   \
        g0[1] = *(const uint4*)(ib + ob0.y + chb);                   \
        g0[2] = *(const uint4*)(ib + ob0.z + chb);                   \
        g0[3] = *(const uint4*)(ib + ob0.w + chb);                   \
        int4 ob1 = moS[(kk) * 64 + px0_ + 8];                        \
        g1[0] = *(const uint4*)(ib + ob1.x + chb);                   \
        g1[1] = *(const uint4*)(ib + ob1.y + chb);                   \
        g1[2] = *(const uint4*)(ib + ob1.z + chb);                   \
        g1[3] = *(const uint4*)(ib + ob1.w + chb);                   \
    }

    // packed-f16 combine: one 2-ch word = 3 hfma2 + 1 hmul2
    #define CMBH(dst_, c00, c01, c10, c11) {                         \
        __half2 a_ = __hmul2(*(__half2*)&(c11), W11);                \
        a_ = __hfma2(*(__half2*)&(c10), W10, a_);                    \
        a_ = __hfma2(*(__half2*)&(c01), W01, a_);                    \
        a_ = __hfma2(*(__half2*)&(c00), W00, a_);                    \
        dst_ = *(unsigned*)&a_;                                      \
    }

    #define COMBINE_STORE(kk, dstb) {                                \
        {                                                            \
            uint4 wp = mw4[(kk) * 64 + px0_];                        \
            __half2 W00 = *(__half2*)&wp.x, W01 = *(__half2*)&wp.y;  \
            __half2 W10 = *(__half2*)&wp.z, W11 = *(__half2*)&wp.w;  \
            uint4 uv;                                                \
            CMBH(uv.x, g0[0].x, g0[1].x, g0[2].x, g0[3].x)           \
            CMBH(uv.y, g0[0].y, g0[1].y, g0[2].y, g0[3].y)           \
            CMBH(uv.z, g0[0].z, g0[1].z, g0[2].z, g0[3].z)           \
            CMBH(uv.w, g0[0].w, g0[1].w, g0[2].w, g0[3].w)           \
            *(uint4*)((dstb) + st_woff[0]) = uv;                     \
        }                                                            \
        {                                                            \
            uint4 wp = mw4[(kk) * 64 + px0_ + 8];                    \
            __half2 W00 = *(__half2*)&wp.x, W01 = *(__half2*)&wp.y;  \
            __half2 W10 = *(__half2*)&wp.z, W11 = *(__half2*)&wp.w;  \
            uint4 uv;                                                \
            CMBH(uv.x, g1[0].x, g1[1].x, g1[2].x, g1[3].x)           \
            CMBH(uv.y, g1[0].y, g1[1].y, g1[2].y, g1[3].y)           \
            CMBH(uv.z, g1[0].z, g1[1].z, g1[2].z, g1[3].z)           \
            CMBH(uv.w, g1[0].w, g1[1].w, g1[2].w, g1[3].w)           \
            *(uint4*)((dstb) + st_woff[1]) = uv;                     \
        }                                                            \
    }

    __syncthreads();   // meta visible

    // ---- prologue: tap 0 (no MFMA to hide under) ----
    ISSUE_TAP(0)
    #pragma unroll
    for (int kf = 0; kf < 2; ++kf) {
        short8 s = *(const short8*)(wt + (((kf * 4 + wv) * 64 + l) << 3));
        wtf[0][kf] = *(half8*)&s;
    }
    COMBINE_STORE(0, smem)
    __syncthreads();

    f32x4 acc[4];
    #pragma unroll
    for (int g = 0; g < 4; ++g) acc[g] = (f32x4){0.f, 0.f, 0.f, 0.f};

    // ---- 9 stages: issue(k+1) / MFMA(k) / combine(k+1), 1 sync each ----
    #pragma unroll
    for (int s = 0; s < 9; ++s) {
        if (s < 8) {
            const int kn = s + 1;
            ISSUE_TAP(kn)
            #pragma unroll
            for (int kf = 0; kf < 2; ++kf) {
                short8 sv = *(const short8*)(wt + ((((kn * 2 + kf) * 4 + wv) * 64 + l) << 3));
                wtf[kn & 1][kf] = *(half8*)&sv;
            }
        }
        __builtin_amdgcn_sched_barrier(0);   // loads stay above (issued early)
        {
            const unsigned char* rb = smem + ((s & 1) << 13);
            #pragma unroll
            for (int g = 0; g < 4; ++g) {
                const int prow = g * 16 + (l & 15);
                short8 a0 = *(const short8*)(rb + prow * 128 + (lq ^ sw));
                short8 a1 = *(const short8*)(rb + prow * 128 + ((64 + lq) ^ sw));
                acc[g] = __builtin_amdgcn_mfma_f32_16x16x32_f16(*(half8*)&a0, wtf[s & 1][0], acc[g], 0, 0, 0);
                acc[g] = __builtin_amdgcn_mfma_f32_16x16x32_f16(*(half8*)&a1, wtf[s & 1][1], acc[g], 0, 0, 0);
            }
        }
        __builtin_amdgcn_sched_barrier(0);   // vmcnt drain lands after the MFMAs
        if (s < 8) {
            COMBINE_STORE(s + 1, smem + (((s + 1) & 1) << 13))
        }
        __syncthreads();
    }
    #undef ISSUE_TAP
    #undef CMBH
    #undef COMBINE_STORE

    // ---- epilogue: swizzled transpose through LDS, coalesced float4 stores ----
    float* out_t = (float*)smem;   // [64 co][256 B rows], XOR-swizzled
    const int cb = wv << 4;
    const int co_e = cb + (l & 15);
    const float bv = bias[co_e];
    const int swE = (co_e & 15) << 4;
    #pragma unroll
    for (int g = 0; g < 4; ++g) {
        int pxb = (g << 6) + ((l >> 4) << 4);   // byte col of pixel group
        float4 v = make_float4(acc[g][0] + bv, acc[g][1] + bv, acc[g][2] + bv, acc[g][3] + bv);
        *(float4*)((unsigned char*)out_t + co_e * 256 + (pxb ^ swE)) = v;
    }
    __syncthreads();
    float* outb = out + (size_t)b * 64 * HW + (size_t)ho * WW + wo0;
    #pragma unroll
    for (int j = 0; j < 4; ++j) {
        int co   = (t >> 4) + (j << 4);
        int colb = (t & 15) << 4;
        float4 v = *(const float4*)((const unsigned char*)out_t + co * 256 + (colb ^ ((co & 15) << 4)));
        *(float4*)&outb[(size_t)co * HW + ((t & 15) << 2)] = v;
    }
}

// -------- fallback (NCHW gather, raw weights, bf16 MFMA) for tiny workspace --------
__global__ __launch_bounds__(256, 4) void deform_fallback(
    const float* __restrict__ x, const float* __restrict__ off,
    const float* __restrict__ msk, const float* __restrict__ wraw,
    const float* __restrict__ bias, float* __restrict__ out)
{
    __shared__ unsigned short s_tile[2][64][68];
    __shared__ __align__(16) unsigned char meta_mem[18432];
    float4* mwS = (float4*)meta_mem;
    int4*   moS = (int4*)(meta_mem + 9216);
    float*  out_t = (float*)meta_mem;

    const int t   = threadIdx.x;
    const int bid = blockIdx.x;
    const int b   = bid & 7;
    const int rem = bid >> 3;
    const int ho  = rem >> 1;
    const int wo0 = (rem & 1) << 6;
    const int l   = t & 63;
    const int wv_id = __builtin_amdgcn_readfirstlane(t >> 6);
    const int c0  = wv_id << 4;
    const int cb  = wv_id << 4;

    short8 wtf[2][2];
    #pragma unroll
    for (int kf = 0; kf < 2; ++kf) {
        short8 f;
        int co = cb + (l & 15);
        int cbase = kf * 32 + (l >> 4) * 8;
        #pragma unroll
        for (int e = 0; e < 8; ++e) f[e] = (short)f2bf(wraw[(co * 64 + cbase + e) * 9 + 0]);
        wtf[0][kf] = f;
    }

    for (int i = t; i < 9 * 64; i += 256) {
        int p = i & 63;
        int k = i >> 6;
        int wo = wo0 + p;
        int obase = ((b * 18 + 2 * k) * HH + ho) * WW + wo;
        float oy = off[obase];
        float ox = off[obase + HW];
        float m  = msk[((b * 9 + k) * HH + ho) * WW + wo];
        float py = oy + (float)(k / 3) + (float)(ho - 1);
        float px = ox + (float)(k % 3) + (float)(wo - 1);
        float fy = floorf(py), fx = floorf(px);
        float ly = py - fy,    lx = px - fx;
        int y0 = (int)fy, x0 = (int)fx;
        int y1 = y0 + 1,  x1 = x0 + 1;
        float vy0 = (y0 >= 0 && y0 < HH) ? 1.f : 0.f;
        float vy1 = (y1 >= 0 && y1 < HH) ? 1.f : 0.f;
        float vx0 = (x0 >= 0 && x0 < WW) ? 1.f : 0.f;
        float vx1 = (x1 >= 0 && x1 < WW) ? 1.f : 0.f;
        float w00 = (1.f - ly) * (1.f - lx) * m * vy0 * vx0;
        float w01 = (1.f - ly) * lx         * m * vy0 * vx1;
        float w10 = ly         * (1.f - lx) * m * vy1 * vx0;
        float w11 = ly         * lx         * m * vy1 * vx1;
        int yc0 = min(max(y0, 0), HH - 1), yc1 = min(max(y1, 0), HH - 1);
        int xc0 = min(max(x0, 0), WW - 1), xc1 = min(max(x1, 0), WW - 1);
        mwS[i] = make_float4(w00, w01, w10, w11);
        moS[i] = make_int4(yc0 * WW + xc0, yc0 * WW + xc1,
                           yc1 * WW + xc0, yc1 * WW + xc1);
    }

    const int p = t & 63;
    const float* xb = x + (size_t)(b * 64 + c0) * HW;
    __syncthreads();

    {
        float4 wv = mwS[p];
        int4   ov = moS[p];
        const float* pc = xb;
        #pragma unroll
        for (int i = 0; i < 16; i += 4) {
            float v0 = wv.x * pc[ov.x] + wv.y * pc[ov.y] + wv.z * pc[ov.z] + wv.w * pc[ov.w]; pc += HW;
            float v1 = wv.x * pc[ov.x] + wv.y * pc[ov.y] + wv.z * pc[ov.z] + wv.w * pc[ov.w]; pc += HW;
            float v2 = wv.x * pc[ov.x] + wv.y * pc[ov.y] + wv.z * pc[ov.z] + wv.w * pc[ov.w]; pc += HW;
            float v3 = wv.x * pc[ov.x] + wv.y * pc[ov.y] + wv.z * pc[ov.z] + wv.w * pc[ov.w]; pc += HW;
            uint2 u;
            u.x = (unsigned)f2bf(v0) | ((unsigned)f2bf(v1) << 16);
            u.y = (unsigned)f2bf(v2) | ((unsigned)f2bf(v3) << 16);
            *(uint2*)&s_tile[0][p][c0 + i] = u;
        }
    }
    __syncthreads();

    f32x4 acc[4];
    #pragma unroll
    for (int g = 0; g < 4; ++g) acc[g] = (f32x4){0.f, 0.f, 0.f, 0.f};

    #pragma unroll
    for (int s = 0; s < 9; ++s) {
        if (s < 8) {
            const int kn = s + 1;
            #pragma unroll
            for (int kf = 0; kf < 2; ++kf) {
                short8 f;
                int co = cb + (l & 15);
                int cbase = kf * 32 + (l >> 4) * 8;
                #pragma unroll
                for (int e = 0; e < 8; ++e) f[e] = (short)f2bf(wraw[(co * 64 + cbase + e) * 9 + kn]);
                wtf[kn & 1][kf] = f;
            }
            float4 wv = mwS[kn * 64 + p];
            int4   ov = moS[kn * 64 + p];
            const float* pc = xb;
            #pragma unroll
            for (int i = 0; i < 16; i += 4) {
                float v0 = wv.x * pc[ov.x] + wv.y * pc[ov.y] + wv.z * pc[ov.z] + wv.w * pc[ov.w]; pc += HW;
                float v1 = wv.x * pc[ov.x] + wv.y * pc[ov.y] + wv.z * pc[ov.z] + wv.w * pc[ov.w]; pc += HW;
                float v2 = wv.x * pc[ov.x] + wv.y * pc[ov.y] + wv.z * pc[ov.z] + wv.w * pc[ov.w]; pc += HW;
                float v3 = wv.x * pc[ov.x] + wv.y * pc[ov.y] + wv.z * pc[ov.z] + wv.w * pc[ov.w]; pc += HW;
                uint2 u;
                u.x = (unsigned)f2bf(v0) | ((unsigned)f2bf(v1) << 16);
                u.y = (unsigned)f2bf(v2) | ((unsigned)f2bf(v3) << 16);
                *(uint2*)&s_tile[kn & 1][p][c0 + i] = u;
            }
        }
        #pragma unroll
        for (int g = 0; g < 4; ++g) {
            const int prow = g * 16 + (l & 15);
            const unsigned short* rp = &s_tile[s & 1][prow][(l >> 4) * 8];
            union { short8 v; unsigned long long q[2]; } ua0, ua1;
            ua0.q[0] = *(const unsigned long long*)(rp);
            ua0.q[1] = *(const unsigned long long*)(rp + 4);
            ua1.q[0] = *(const unsigned long long*)(rp + 32);
            ua1.q[1] = *(const unsigned long long*)(rp + 36);
            acc[g] = __builtin_amdgcn_mfma_f32_16x16x32_bf16(ua0.v, wtf[s & 1][0], acc[g], 0, 0, 0);
            acc[g] = __builtin_amdgcn_mfma_f32_16x16x32_bf16(ua1.v, wtf[s & 1][1], acc[g], 0, 0, 0);
        }
        __syncthreads();
    }

    const float bv = bias[cb + (l & 15)];
    #pragma unroll
    for (int g = 0; g < 4; ++g) {
        int co = cb + (l & 15);
        int pxb = g * 16 + (l >> 4) * 4;
        #pragma unroll
        for (int r = 0; r < 4; ++r)
            out_t[co * 68 + pxb + r] = acc[g][r] + bv;
    }
    __syncthreads();
    float* outb = out + (size_t)b * 64 * HW + (size_t)ho * WW + wo0;
    #pragma unroll
    for (int j = 0; j < 4; ++j) {
        int co  = (t >> 4) + j * 16;
        int px0 = (t & 15) << 2;
        float4 v = *(float4*)&out_t[co * 68 + px0];
        *(float4*)&outb[(size_t)co * HW + px0] = v;
    }
}

extern "C" void kernel_launch(void* const* d_in, const int* in_sizes, int n_in,
                              void* d_out, int out_size, void* d_ws, size_t ws_size,
                              hipStream_t stream) {
    const float* x    = (const float*)d_in[0];
    const float* off  = (const float*)d_in[1];
    const float* msk  = (const float*)d_in[2];
    const float* w    = (const float*)d_in[3];
    const float* bias = (const float*)d_in[4];
    float* out = (float*)d_out;

    const size_t need = XT_BYTES + WT_BYTES;
    if (d_ws != nullptr && ws_size >= need) {
        unsigned int*   xt32 = (unsigned int*)d_ws;
        unsigned short* wt   = (unsigned short*)((char*)d_ws + XT_BYTES);
        xtrans_kernel<<<2048, 256, 0, stream>>>(x, xt32);
        wtrans_kernel<<<144, 256, 0, stream>>>(w, wt);
        deform_nhwc<<<2048, 256, 0, stream>>>((const unsigned short*)xt32, off, msk, wt, bias, out);
    } else {
        deform_fallback<<<2048, 256, 0, stream>>>(x, off, msk, w, bias, out);
    }
}